// Round 1
// baseline (55.716 us; speedup 1.0000x reference)
//
#include <hip/hip_runtime.h>
#include <hip/hip_bf16.h>

#define HH 512
#define LL 1024
#define CC 512
#define NREL 51

typedef __attribute__((ext_vector_type(8))) short bf16x8;
typedef __attribute__((ext_vector_type(4))) float f32x4;

__device__ __forceinline__ short f2bn(float f) {
    return __builtin_bit_cast(short, __float2bfloat16(f));   // native RNE cvt
}

// async global->LDS, 16B per lane; lds arg = wave-uniform base (lane i lands at +16i)
__device__ __forceinline__ void gl16(const void* g, void* l) {
    __builtin_amdgcn_global_load_lds(
        (const __attribute__((address_space(1))) void*)g,
        (__attribute__((address_space(3))) void*)l, 16, 0, 0);
}

// ---------------------------------------------------------------------------
// K0: f32 -> bf16 convert of all GEMM operands, stored PRE-SWIZZLED (T21/T2).
// NEW: zeroes Rbuf (65536 f32) + cnt (64 int) for k1's atomic partial-R and
// k2's last-block counter (re-zeroed every graph replay), and zeroes relkb
// rows 51..63 so the R-partial MFMA never eats workspace poison.
// ---------------------------------------------------------------------------
__global__ __launch_bounds__(256) void k0_prep(
    const float* __restrict__ query, const float* __restrict__ key,
    const float* __restrict__ Wq, const float* __restrict__ Wk,
    const float* __restrict__ relk,
    short* __restrict__ queryb, short* __restrict__ keyb,
    short* __restrict__ Wqb, short* __restrict__ Wkb, short* __restrict__ relkb,
    float* __restrict__ zbase)
{
    const int z = blockIdx.x * 256 + threadIdx.x;
    const float4 zz = make_float4(0.f, 0.f, 0.f, 0.f);
    if (z < 16400) ((float4*)zbase)[z] = zz;              // Rbuf + cnt
    if (z < 832)  ((float4*)(relkb + 51 * HH))[z] = zz;   // relkb poison rows
    for (int u = blockIdx.x * 256 + threadIdx.x; u < 167104; u += 131072) {
        const float* src; short* dst; int c;
        if (u < 65536)       { src = query; dst = queryb; c = u; }
        else if (u < 98304)  { src = key;   dst = keyb;   c = u - 65536; }
        else if (u < 131072) { src = Wq;    dst = Wqb;    c = u - 98304; }
        else if (u < 163840) { src = Wk;    dst = Wkb;    c = u - 131072; }
        else                 { src = relk;  dst = relkb;  c = u - 163840; }
        float4 x = *(const float4*)(src + c * 8);
        float4 y = *(const float4*)(src + c * 8 + 4);
        bf16x8 o;
        o[0] = f2bn(x.x); o[1] = f2bn(x.y); o[2] = f2bn(x.z); o[3] = f2bn(x.w);
        o[4] = f2bn(y.x); o[5] = f2bn(y.y); o[6] = f2bn(y.z); o[7] = f2bn(y.w);
        const int cs = c ^ ((c >> 6) & 7);          // swizzle within the 64-chunk row
        *(bf16x8*)(dst + cs * 8) = o;
    }
}

// ---------------------------------------------------------------------------
// K1: q = bf16(query@Wq.T + bq) [blocks 0..511], k = bf16(key@Wk.T) [512..767]
// (bk dropped: per-row constant, softmax-invariant). 1 wave/block, tile 16x64,
// BK=64, 8 steps, counted vmcnt(10) pipeline (T4).
// NEW: q-blocks also compute their 64-h partial of R = q @ relk^T (the block's
// 64 output cols ARE 64 elements of R's contraction axis): relk slice staged at
// kernel start (lands under the main pipeline), q-tile round-trips through LDS
// into A-frag layout, one K=64 MFMA step, f32 atomicAdd into global Rbuf.
// This kills the 8x-redundant racc in k2.
// ---------------------------------------------------------------------------
__global__ __launch_bounds__(64) void k1_proj(
    const short* __restrict__ queryb, const short* __restrict__ keyb,
    const short* __restrict__ Wqb, const short* __restrict__ Wkb,
    const short* __restrict__ relkb, const float* __restrict__ bq,
    short* __restrict__ qbuf, short* __restrict__ kbuf,
    float* __restrict__ Rbuf)
{
    __shared__ __align__(16) short buf[2][5120];   // [A 16x64 | B 64x64] shorts
    __shared__ __align__(16) short rl[5120];       // [relk 64x64 | q-tile 16x64]
    const int b = blockIdx.x, l = threadIdx.x;
    const bool isq = (b < 512);
    const short *A, *B; short* outp; int m0, n0;
    if (isq) { A = queryb; B = Wqb; outp = qbuf;
               m0 = (b >> 3) * 16; n0 = (b & 7) * 64; }
    else     { const int bb = b - 512; A = keyb; B = Wkb; outp = kbuf;
               m0 = (bb >> 3) * 16; n0 = (bb & 7) * 64; }
    const int lr = l & 15, lk = (l >> 4) * 8;
    const int lx = 8 * (lr & 7);                   // frag-read swizzle
    const int srow = l >> 3, scol = (l & 7) * 8;   // staging lane->elem map

    // relk slice [64 rel x 64 h] for the partial-R step: issued FIRST, so it is
    // the oldest vmem op -> every counted vmcnt below implicitly drains it too.
    if (isq) {
        #pragma unroll
        for (int j = 0; j < 8; ++j)
            gl16(relkb + (j * 8 + srow) * HH + n0 + scol, rl + j * 512);
    }

#define K1_STAGE(bi, t) do { \
        const int k0 = (t) * 64; \
        short* Lb = buf[bi]; \
        _Pragma("unroll") \
        for (int j = 0; j < 2; ++j) \
            gl16(A + (m0 + j * 8 + srow) * HH + k0 + scol, Lb + j * 512); \
        _Pragma("unroll") \
        for (int j = 0; j < 8; ++j) \
            gl16(B + (n0 + j * 8 + srow) * HH + k0 + scol, Lb + 1024 + j * 512); \
    } while (0)

    f32x4 acc[4] = {};
#define K1_COMP(bi) do { \
        const short* Lb = buf[bi]; \
        bf16x8 a0 = *(const bf16x8*)(Lb + lr * 64 + ((0 + lk) ^ lx)); \
        bf16x8 a1 = *(const bf16x8*)(Lb + lr * 64 + ((32 + lk) ^ lx)); \
        _Pragma("unroll") \
        for (int f = 0; f < 4; ++f) { \
            bf16x8 b0 = *(const bf16x8*)(Lb + 1024 + (f * 16 + lr) * 64 + ((0 + lk) ^ lx)); \
            bf16x8 b1 = *(const bf16x8*)(Lb + 1024 + (f * 16 + lr) * 64 + ((32 + lk) ^ lx)); \
            acc[f] = __builtin_amdgcn_mfma_f32_16x16x32_bf16(a0, b0, acc[f], 0, 0, 0); \
            acc[f] = __builtin_amdgcn_mfma_f32_16x16x32_bf16(a1, b1, acc[f], 0, 0, 0); \
        } \
    } while (0)

    K1_STAGE(0, 0);
    #pragma unroll
    for (int t = 0; t < 8; ++t) {
        if (t < 7) {
            K1_STAGE((t + 1) & 1, t + 1);
            asm volatile("s_waitcnt vmcnt(10)" ::: "memory");   // tile t landed; t+1 in flight
        } else {
            asm volatile("s_waitcnt vmcnt(0)" ::: "memory");
        }
        __builtin_amdgcn_sched_barrier(0);
        K1_COMP(t & 1);
    }
#undef K1_STAGE
#undef K1_COMP

    if (isq) {
        short* qt = rl + 4096;
        #pragma unroll
        for (int f = 0; f < 4; ++f) {
            const int colg = f * 16 + lr;
            const float bv = bq[n0 + colg];
            #pragma unroll
            for (int r = 0; r < 4; ++r) {
                const int row = (l >> 4) * 4 + r;
                const short h = f2bn(acc[f][r] + bv);
                outp[(m0 + row) * HH + n0 + (colg ^ (8 * (row & 7)))] = h;
                // C-layout -> A-tile layout in LDS (same chunk-XOR swizzle)
                qt[row * 64 + (((colg >> 3) ^ (row & 7)) << 3) + (colg & 7)] = h;
            }
        }
        // partial R over this block's 64 h-cols (relk landed: final vmcnt(0) above)
        f32x4 racc[4] = {};
        bf16x8 a0 = *(const bf16x8*)(qt + lr * 64 + ((0 + lk) ^ lx));
        bf16x8 a1 = *(const bf16x8*)(qt + lr * 64 + ((32 + lk) ^ lx));
        #pragma unroll
        for (int f = 0; f < 4; ++f) {
            bf16x8 b0 = *(const bf16x8*)(rl + (f * 16 + lr) * 64 + ((0 + lk) ^ lx));
            bf16x8 b1 = *(const bf16x8*)(rl + (f * 16 + lr) * 64 + ((32 + lk) ^ lx));
            racc[f] = __builtin_amdgcn_mfma_f32_16x16x32_bf16(a0, b0, racc[f], 0, 0, 0);
            racc[f] = __builtin_amdgcn_mfma_f32_16x16x32_bf16(a1, b1, racc[f], 0, 0, 0);
        }
        #pragma unroll
        for (int f = 0; f < 4; ++f)
            #pragma unroll
            for (int r = 0; r < 4; ++r)
                atomicAdd(Rbuf + (m0 + (l >> 4) * 4 + r) * 64 + f * 16 + lr,
                          racc[f][r]);
    } else {
        #pragma unroll
        for (int f = 0; f < 4; ++f) {
            const int colg = f * 16 + lr;
            #pragma unroll
            for (int r = 0; r < 4; ++r) {
                const int row = m0 + (l >> 4) * 4 + r;
                outp[row * HH + n0 + (colg ^ (8 * (row & 7)))] = f2bn(acc[f][r]);
            }
        }
    }
}

// ---------------------------------------------------------------------------
// K2: 512 blocks (64 row-groups x 8 col-groups), 1 wave each, tile 16x64.
// LEAN: qk MFMA only (racc moved to k1) -> 10 gload / 10 ds_read / 8 MFMA per
// step (was 18/18/16), depth-3 counted vmcnt(20). R gathered from Rbuf (L2-hot)
// at t==6 so its latency drains with the final vmcnt(0). Then rel gather,
// max-free exp, per-cg row sums -> Ssum, unnormalized out.
// NEW: last-block-per-rowgroup normalization (replaces k3): threadfence +
// agent-scope atomic counter; 8th block re-reads the 16x512 row block and
// scales by 1/sum of the 8 partials.
// ---------------------------------------------------------------------------
__global__ __launch_bounds__(64) void k2_attn(
    const short* __restrict__ qbuf, const short* __restrict__ kbuf,
    const int* __restrict__ rel, const int* __restrict__ qlen,
    const float* __restrict__ Rbuf, float* __restrict__ Ssum,
    int* __restrict__ cnt, float* __restrict__ out)
{
    __shared__ __align__(16) short buf[3][5120];  // [A 1024 | Bk 4096] x3
    const int b = blockIdx.x, l = threadIdx.x;
    const int l0 = (b >> 3) * 16, cg = b & 7, cb = cg * 64;
    const int lr = l & 15, lk = (l >> 4) * 8;
    const int lx = 8 * (lr & 7);
    const int srow = l >> 3, scol = (l & 7) * 8;
    const int qoff = qlen[0];

    // hoisted rel gather indices (latency hides under the K-loop)
    int idxr[4][4];
    #pragma unroll
    for (int r = 0; r < 4; ++r) {
        const int row = (l >> 4) * 4 + r;
        #pragma unroll
        for (int f = 0; f < 4; ++f)
            idxr[r][f] = rel[(l0 + row) * LL + qoff + cb + f * 16 + lr];
    }

#define K2_STAGE(bi, t) do { \
        const int k0 = (t) * 64; \
        short* Lb = buf[bi]; \
        _Pragma("unroll") \
        for (int j = 0; j < 2; ++j) \
            gl16(qbuf + (l0 + j * 8 + srow) * HH + k0 + scol, Lb + j * 512); \
        _Pragma("unroll") \
        for (int j = 0; j < 8; ++j) \
            gl16(kbuf + (cb + j * 8 + srow) * HH + k0 + scol, Lb + 1024 + j * 512); \
    } while (0)

    f32x4 acc[4] = {};
#define K2_COMP(bi) do { \
        const short* Lb = buf[bi]; \
        bf16x8 a0 = *(const bf16x8*)(Lb + lr * 64 + ((0 + lk) ^ lx)); \
        bf16x8 a1 = *(const bf16x8*)(Lb + lr * 64 + ((32 + lk) ^ lx)); \
        _Pragma("unroll") \
        for (int f = 0; f < 4; ++f) { \
            const int ro = (f * 16 + lr) * 64; \
            bf16x8 k0v = *(const bf16x8*)(Lb + 1024 + ro + ((0 + lk) ^ lx)); \
            bf16x8 k1v = *(const bf16x8*)(Lb + 1024 + ro + ((32 + lk) ^ lx)); \
            acc[f] = __builtin_amdgcn_mfma_f32_16x16x32_bf16(a0, k0v, acc[f], 0, 0, 0); \
            acc[f] = __builtin_amdgcn_mfma_f32_16x16x32_bf16(a1, k1v, acc[f], 0, 0, 0); \
        } \
    } while (0)

    float rv[4][4];
    K2_STAGE(0, 0); K2_STAGE(1, 1);
    #pragma unroll
    for (int t = 0; t < 8; ++t) {
        if (t < 6) {
            K2_STAGE((t + 2) % 3, t + 2);
            asm volatile("s_waitcnt vmcnt(20)" ::: "memory");   // tile t landed; t+1,t+2 in flight
        } else if (t == 6) {
            asm volatile("s_waitcnt vmcnt(10)" ::: "memory");
            // idxr landed long ago (oldest vmem, in-order count): issue the
            // Rbuf gather now; it drains with t==7's vmcnt(0).
            #pragma unroll
            for (int r = 0; r < 4; ++r)
                #pragma unroll
                for (int f = 0; f < 4; ++f)
                    rv[r][f] = Rbuf[(l0 + (l >> 4) * 4 + r) * 64 + idxr[r][f]];
        } else {
            asm volatile("s_waitcnt vmcnt(0)" ::: "memory");
        }
        __builtin_amdgcn_sched_barrier(0);
        K2_COMP(t % 3);
    }
#undef K2_STAGE
#undef K2_COMP

    const float scale = 0.04419417382415922f;   // 1/sqrt(512)
    #pragma unroll
    for (int r = 0; r < 4; ++r) {
        const int row = (l >> 4) * 4 + r;
        float s = 0.f;
        #pragma unroll
        for (int f = 0; f < 4; ++f) {
            float e = __expf((acc[f][r] + rv[r][f]) * scale);
            acc[f][r] = e; s += e;
        }
        #pragma unroll
        for (int sh = 1; sh < 16; sh <<= 1) s += __shfl_xor(s, sh, 64);
        if (lr == 0) Ssum[(l0 + row) * 8 + cg] = s;
    }
    #pragma unroll
    for (int f = 0; f < 4; ++f)
        #pragma unroll
        for (int r = 0; r < 4; ++r) {
            const int row = (l >> 4) * 4 + r;
            out[(l0 + row) * CC + cb + f * 16 + lr] = acc[f][r];
        }

    // ---- last block for this row-group normalizes (replaces k3) ----
    __threadfence();                                    // release out + Ssum
    int old = 0;
    if (l == 0)
        old = __hip_atomic_fetch_add(&cnt[b >> 3], 1, __ATOMIC_ACQ_REL,
                                     __HIP_MEMORY_SCOPE_AGENT);
    old = __shfl(old, 0, 64);
    if (old == 7) {
        __threadfence();                                // acquire peers' writes
        float inv = 1.f;
        if (l < 16) {
            const float* sp = Ssum + (l0 + l) * 8;
            inv = 1.f / (sp[0] + sp[1] + sp[2] + sp[3] +
                         sp[4] + sp[5] + sp[6] + sp[7]);
        }
        #pragma unroll
        for (int row = 0; row < 16; ++row) {
            const float iv = __shfl(inv, row, 64);
            float4* po = (float4*)(out + (l0 + row) * CC);
            float4 v0 = po[l], v1 = po[l + 64];
            v0.x *= iv; v0.y *= iv; v0.z *= iv; v0.w *= iv;
            v1.x *= iv; v1.y *= iv; v1.z *= iv; v1.w *= iv;
            po[l] = v0; po[l + 64] = v1;
        }
    }
}

extern "C" void kernel_launch(void* const* d_in, const int* in_sizes, int n_in,
                              void* d_out, int out_size, void* d_ws, size_t ws_size,
                              hipStream_t stream) {
    const float* query = (const float*)d_in[0];
    const float* key   = (const float*)d_in[1];
    const int*   rel   = (const int*)d_in[3];
    const int*   qlen  = (const int*)d_in[4];
    const float* Wq    = (const float*)d_in[6];
    const float* bq    = (const float*)d_in[7];
    const float* Wk    = (const float*)d_in[8];
    const float* relk  = (const float*)d_in[12];

    float* out = (float*)d_out;
    short* p = (short*)d_ws;
    short* queryb = p;  p += LL * HH;    // 524288
    short* keyb   = p;  p += CC * HH;    // 262144
    short* Wqb    = p;  p += HH * HH;    // 262144
    short* Wkb    = p;  p += HH * HH;    // 262144
    short* relkb  = p;  p += 64 * HH;    // 32768 (51 rows valid, tail zeroed)
    short* qbuf   = p;  p += LL * HH;    // 524288
    short* kbuf   = p;  p += CC * HH;    // 262144
    float* Ssum   = (float*)p;           // 1024*8 f32
    float* Rbuf   = Ssum + LL * 8;       // 1024*64 f32 (R = q @ relk^T)
    int*   cnt    = (int*)(Rbuf + LL * 64); // 64 row-group counters

    k0_prep<<<512, 256, 0, stream>>>(query, key, Wq, Wk, relk,
                                     queryb, keyb, Wqb, Wkb, relkb, Rbuf);
    k1_proj<<<768, 64, 0, stream>>>(queryb, keyb, Wqb, Wkb, relkb, bq,
                                    qbuf, kbuf, Rbuf);
    k2_attn<<<512, 64, 0, stream>>>(qbuf, kbuf, rel, qlen, Rbuf, Ssum, cnt, out);
}

// Round 2
// 25.840 us; speedup vs baseline: 2.1562x; 2.1562x over previous
//
#include <hip/hip_runtime.h>
#include <hip/hip_bf16.h>

#define HH 512
#define LL 1024
#define CC 512
#define NREL 51

typedef __attribute__((ext_vector_type(8))) short bf16x8;
typedef __attribute__((ext_vector_type(4))) float f32x4;

__device__ __forceinline__ short f2bn(float f) {
    return __builtin_bit_cast(short, __float2bfloat16(f));   // native RNE cvt
}

// async global->LDS, 16B per lane; lds arg = wave-uniform base (lane i lands at +16i)
__device__ __forceinline__ void gl16(const void* g, void* l) {
    __builtin_amdgcn_global_load_lds(
        (const __attribute__((address_space(1))) void*)g,
        (__attribute__((address_space(3))) void*)l, 16, 0, 0);
}

// ---------------------------------------------------------------------------
// K0: f32 -> bf16 convert of all GEMM operands, stored PRE-SWIZZLED (T21/T2).
// Also zeroes Rbuf (65536 f32) for k1's atomic partial-R accumulation
// (re-zeroed every graph replay) and relkb rows 51..63 (poison guard).
// ---------------------------------------------------------------------------
__global__ __launch_bounds__(256) void k0_prep(
    const float* __restrict__ query, const float* __restrict__ key,
    const float* __restrict__ Wq, const float* __restrict__ Wk,
    const float* __restrict__ relk,
    short* __restrict__ queryb, short* __restrict__ keyb,
    short* __restrict__ Wqb, short* __restrict__ Wkb, short* __restrict__ relkb,
    float* __restrict__ Rbuf)
{
    const int z = blockIdx.x * 256 + threadIdx.x;
    const float4 zz = make_float4(0.f, 0.f, 0.f, 0.f);
    if (z < 16384) ((float4*)Rbuf)[z] = zz;               // Rbuf
    if (z < 832)  ((float4*)(relkb + 51 * HH))[z] = zz;   // relkb poison rows
    for (int u = blockIdx.x * 256 + threadIdx.x; u < 167104; u += 131072) {
        const float* src; short* dst; int c;
        if (u < 65536)       { src = query; dst = queryb; c = u; }
        else if (u < 98304)  { src = key;   dst = keyb;   c = u - 65536; }
        else if (u < 131072) { src = Wq;    dst = Wqb;    c = u - 98304; }
        else if (u < 163840) { src = Wk;    dst = Wkb;    c = u - 131072; }
        else                 { src = relk;  dst = relkb;  c = u - 163840; }
        float4 x = *(const float4*)(src + c * 8);
        float4 y = *(const float4*)(src + c * 8 + 4);
        bf16x8 o;
        o[0] = f2bn(x.x); o[1] = f2bn(x.y); o[2] = f2bn(x.z); o[3] = f2bn(x.w);
        o[4] = f2bn(y.x); o[5] = f2bn(y.y); o[6] = f2bn(y.z); o[7] = f2bn(y.w);
        const int cs = c ^ ((c >> 6) & 7);          // swizzle within the 64-chunk row
        *(bf16x8*)(dst + cs * 8) = o;
    }
}

// ---------------------------------------------------------------------------
// K1: q = bf16(query@Wq.T + bq) [blocks 0..511], k = bf16(key@Wk.T) [512..767]
// (bk dropped: per-row constant, softmax-invariant). 1 wave/block, tile 16x64,
// BK=64, 8 steps, counted vmcnt(10) pipeline (T4).
// q-blocks also compute their 64-h partial of R = q @ relk^T (the block's 64
// output cols ARE 64 elements of R's contraction axis): relk slice staged at
// kernel start (oldest vmem op -> drained by the first counted vmcnt), q-tile
// round-trips through LDS into A-frag layout, one K=64 MFMA step, f32
// atomicAdd into global Rbuf (disjoint-in-time 8-way conflicts only).
// ---------------------------------------------------------------------------
__global__ __launch_bounds__(64) void k1_proj(
    const short* __restrict__ queryb, const short* __restrict__ keyb,
    const short* __restrict__ Wqb, const short* __restrict__ Wkb,
    const short* __restrict__ relkb, const float* __restrict__ bq,
    short* __restrict__ qbuf, short* __restrict__ kbuf,
    float* __restrict__ Rbuf)
{
    __shared__ __align__(16) short buf[2][5120];   // [A 16x64 | B 64x64] shorts
    __shared__ __align__(16) short rl[5120];       // [relk 64x64 | q-tile 16x64]
    const int b = blockIdx.x, l = threadIdx.x;
    const bool isq = (b < 512);
    const short *A, *B; short* outp; int m0, n0;
    if (isq) { A = queryb; B = Wqb; outp = qbuf;
               m0 = (b >> 3) * 16; n0 = (b & 7) * 64; }
    else     { const int bb = b - 512; A = keyb; B = Wkb; outp = kbuf;
               m0 = (bb >> 3) * 16; n0 = (bb & 7) * 64; }
    const int lr = l & 15, lk = (l >> 4) * 8;
    const int lx = 8 * (lr & 7);                   // frag-read swizzle
    const int srow = l >> 3, scol = (l & 7) * 8;   // staging lane->elem map

    // relk slice [64 rel x 64 h] for the partial-R step: issued FIRST, so it is
    // the oldest vmem op -> the first counted vmcnt below drains it too.
    if (isq) {
        #pragma unroll
        for (int j = 0; j < 8; ++j)
            gl16(relkb + (j * 8 + srow) * HH + n0 + scol, rl + j * 512);
    }

#define K1_STAGE(bi, t) do { \
        const int k0 = (t) * 64; \
        short* Lb = buf[bi]; \
        _Pragma("unroll") \
        for (int j = 0; j < 2; ++j) \
            gl16(A + (m0 + j * 8 + srow) * HH + k0 + scol, Lb + j * 512); \
        _Pragma("unroll") \
        for (int j = 0; j < 8; ++j) \
            gl16(B + (n0 + j * 8 + srow) * HH + k0 + scol, Lb + 1024 + j * 512); \
    } while (0)

    f32x4 acc[4] = {};
#define K1_COMP(bi) do { \
        const short* Lb = buf[bi]; \
        bf16x8 a0 = *(const bf16x8*)(Lb + lr * 64 + ((0 + lk) ^ lx)); \
        bf16x8 a1 = *(const bf16x8*)(Lb + lr * 64 + ((32 + lk) ^ lx)); \
        _Pragma("unroll") \
        for (int f = 0; f < 4; ++f) { \
            bf16x8 b0 = *(const bf16x8*)(Lb + 1024 + (f * 16 + lr) * 64 + ((0 + lk) ^ lx)); \
            bf16x8 b1 = *(const bf16x8*)(Lb + 1024 + (f * 16 + lr) * 64 + ((32 + lk) ^ lx)); \
            acc[f] = __builtin_amdgcn_mfma_f32_16x16x32_bf16(a0, b0, acc[f], 0, 0, 0); \
            acc[f] = __builtin_amdgcn_mfma_f32_16x16x32_bf16(a1, b1, acc[f], 0, 0, 0); \
        } \
    } while (0)

    K1_STAGE(0, 0);
    #pragma unroll
    for (int t = 0; t < 8; ++t) {
        if (t < 7) {
            K1_STAGE((t + 1) & 1, t + 1);
            asm volatile("s_waitcnt vmcnt(10)" ::: "memory");   // tile t landed; t+1 in flight
        } else {
            asm volatile("s_waitcnt vmcnt(0)" ::: "memory");
        }
        __builtin_amdgcn_sched_barrier(0);
        K1_COMP(t & 1);
    }
#undef K1_STAGE
#undef K1_COMP

    if (isq) {
        short* qt = rl + 4096;
        #pragma unroll
        for (int f = 0; f < 4; ++f) {
            const int colg = f * 16 + lr;
            const float bv = bq[n0 + colg];
            #pragma unroll
            for (int r = 0; r < 4; ++r) {
                const int row = (l >> 4) * 4 + r;
                const short h = f2bn(acc[f][r] + bv);
                outp[(m0 + row) * HH + n0 + (colg ^ (8 * (row & 7)))] = h;
                // C-layout -> A-tile layout in LDS (same chunk-XOR swizzle)
                qt[row * 64 + (((colg >> 3) ^ (row & 7)) << 3) + (colg & 7)] = h;
            }
        }
        // partial R over this block's 64 h-cols (relk landed: final vmcnt(0) above)
        f32x4 racc[4] = {};
        bf16x8 a0 = *(const bf16x8*)(qt + lr * 64 + ((0 + lk) ^ lx));
        bf16x8 a1 = *(const bf16x8*)(qt + lr * 64 + ((32 + lk) ^ lx));
        #pragma unroll
        for (int f = 0; f < 4; ++f) {
            bf16x8 b0 = *(const bf16x8*)(rl + (f * 16 + lr) * 64 + ((0 + lk) ^ lx));
            bf16x8 b1 = *(const bf16x8*)(rl + (f * 16 + lr) * 64 + ((32 + lk) ^ lx));
            racc[f] = __builtin_amdgcn_mfma_f32_16x16x32_bf16(a0, b0, racc[f], 0, 0, 0);
            racc[f] = __builtin_amdgcn_mfma_f32_16x16x32_bf16(a1, b1, racc[f], 0, 0, 0);
        }
        #pragma unroll
        for (int f = 0; f < 4; ++f)
            #pragma unroll
            for (int r = 0; r < 4; ++r)
                atomicAdd(Rbuf + (m0 + (l >> 4) * 4 + r) * 64 + f * 16 + lr,
                          racc[f][r]);
    } else {
        #pragma unroll
        for (int f = 0; f < 4; ++f) {
            const int colg = f * 16 + lr;
            #pragma unroll
            for (int r = 0; r < 4; ++r) {
                const int row = m0 + (l >> 4) * 4 + r;
                outp[row * HH + n0 + (colg ^ (8 * (row & 7)))] = f2bn(acc[f][r]);
            }
        }
    }
}

// ---------------------------------------------------------------------------
// K2: 512 blocks (64 row-groups x 8 col-groups), 1 wave each, tile 16x64.
// LEAN: qk MFMA only (racc moved to k1) -> 10 gload / 10 ds_read / 8 MFMA per
// step (was 18/18/16), depth-3 counted vmcnt(20). R gathered from Rbuf (L2-hot)
// at t==6 so its latency drains with the final vmcnt(0). Then max-free exp,
// per-cg row sums -> Ssum, unnormalized out. NO cross-block fencing (round-1
// lesson: agent-scope __threadfence on multi-XCD = L2 wbinv, 49us stall);
// normalization stays in k3 behind the kernel boundary.
// ---------------------------------------------------------------------------
__global__ __launch_bounds__(64) void k2_attn(
    const short* __restrict__ qbuf, const short* __restrict__ kbuf,
    const int* __restrict__ rel, const int* __restrict__ qlen,
    const float* __restrict__ Rbuf, float* __restrict__ Ssum,
    float* __restrict__ out)
{
    __shared__ __align__(16) short buf[3][5120];  // [A 1024 | Bk 4096] x3
    const int b = blockIdx.x, l = threadIdx.x;
    const int l0 = (b >> 3) * 16, cg = b & 7, cb = cg * 64;
    const int lr = l & 15, lk = (l >> 4) * 8;
    const int lx = 8 * (lr & 7);
    const int srow = l >> 3, scol = (l & 7) * 8;
    const int qoff = qlen[0];

    // hoisted rel gather indices (latency hides under the K-loop)
    int idxr[4][4];
    #pragma unroll
    for (int r = 0; r < 4; ++r) {
        const int row = (l >> 4) * 4 + r;
        #pragma unroll
        for (int f = 0; f < 4; ++f)
            idxr[r][f] = rel[(l0 + row) * LL + qoff + cb + f * 16 + lr];
    }

#define K2_STAGE(bi, t) do { \
        const int k0 = (t) * 64; \
        short* Lb = buf[bi]; \
        _Pragma("unroll") \
        for (int j = 0; j < 2; ++j) \
            gl16(qbuf + (l0 + j * 8 + srow) * HH + k0 + scol, Lb + j * 512); \
        _Pragma("unroll") \
        for (int j = 0; j < 8; ++j) \
            gl16(kbuf + (cb + j * 8 + srow) * HH + k0 + scol, Lb + 1024 + j * 512); \
    } while (0)

    f32x4 acc[4] = {};
#define K2_COMP(bi) do { \
        const short* Lb = buf[bi]; \
        bf16x8 a0 = *(const bf16x8*)(Lb + lr * 64 + ((0 + lk) ^ lx)); \
        bf16x8 a1 = *(const bf16x8*)(Lb + lr * 64 + ((32 + lk) ^ lx)); \
        _Pragma("unroll") \
        for (int f = 0; f < 4; ++f) { \
            const int ro = (f * 16 + lr) * 64; \
            bf16x8 k0v = *(const bf16x8*)(Lb + 1024 + ro + ((0 + lk) ^ lx)); \
            bf16x8 k1v = *(const bf16x8*)(Lb + 1024 + ro + ((32 + lk) ^ lx)); \
            acc[f] = __builtin_amdgcn_mfma_f32_16x16x32_bf16(a0, k0v, acc[f], 0, 0, 0); \
            acc[f] = __builtin_amdgcn_mfma_f32_16x16x32_bf16(a1, k1v, acc[f], 0, 0, 0); \
        } \
    } while (0)

    float rv[4][4];
    K2_STAGE(0, 0); K2_STAGE(1, 1);
    #pragma unroll
    for (int t = 0; t < 8; ++t) {
        if (t < 6) {
            K2_STAGE((t + 2) % 3, t + 2);
            asm volatile("s_waitcnt vmcnt(20)" ::: "memory");   // tile t landed; t+1,t+2 in flight
        } else if (t == 6) {
            asm volatile("s_waitcnt vmcnt(10)" ::: "memory");
            // idxr landed long ago (oldest vmem, in-order count): issue the
            // Rbuf gather now; it drains with t==7's vmcnt(0).
            #pragma unroll
            for (int r = 0; r < 4; ++r)
                #pragma unroll
                for (int f = 0; f < 4; ++f)
                    rv[r][f] = Rbuf[(l0 + (l >> 4) * 4 + r) * 64 + idxr[r][f]];
        } else {
            asm volatile("s_waitcnt vmcnt(0)" ::: "memory");
        }
        __builtin_amdgcn_sched_barrier(0);
        K2_COMP(t % 3);
    }
#undef K2_STAGE
#undef K2_COMP

    const float scale = 0.04419417382415922f;   // 1/sqrt(512)
    #pragma unroll
    for (int r = 0; r < 4; ++r) {
        const int row = (l >> 4) * 4 + r;
        float s = 0.f;
        #pragma unroll
        for (int f = 0; f < 4; ++f) {
            float e = __expf((acc[f][r] + rv[r][f]) * scale);
            acc[f][r] = e; s += e;
        }
        #pragma unroll
        for (int sh = 1; sh < 16; sh <<= 1) s += __shfl_xor(s, sh, 64);
        if (lr == 0) Ssum[(l0 + row) * 8 + cg] = s;
    }
    #pragma unroll
    for (int f = 0; f < 4; ++f)
        #pragma unroll
        for (int r = 0; r < 4; ++r) {
            const int row = (l >> 4) * 4 + r;
            out[(l0 + row) * CC + cb + f * 16 + lr] = acc[f][r];
        }
}

// K3: out[row][*] /= sum of the row's 8 partial sums.
__global__ __launch_bounds__(256) void k3_norm(
    const float* __restrict__ Ssum, float* __restrict__ out)
{
    const int e = (blockIdx.x * 256 + threadIdx.x) * 4;
    const int row = e >> 9;
    float4 s0 = *(const float4*)(Ssum + row * 8);
    float4 s1 = *(const float4*)(Ssum + row * 8 + 4);
    const float inv = 1.f / (s0.x + s0.y + s0.z + s0.w + s1.x + s1.y + s1.z + s1.w);
    float4 v = *(float4*)(out + e);
    v.x *= inv; v.y *= inv; v.z *= inv; v.w *= inv;
    *(float4*)(out + e) = v;
}

extern "C" void kernel_launch(void* const* d_in, const int* in_sizes, int n_in,
                              void* d_out, int out_size, void* d_ws, size_t ws_size,
                              hipStream_t stream) {
    const float* query = (const float*)d_in[0];
    const float* key   = (const float*)d_in[1];
    const int*   rel   = (const int*)d_in[3];
    const int*   qlen  = (const int*)d_in[4];
    const float* Wq    = (const float*)d_in[6];
    const float* bq    = (const float*)d_in[7];
    const float* Wk    = (const float*)d_in[8];
    const float* relk  = (const float*)d_in[12];

    float* out = (float*)d_out;
    short* p = (short*)d_ws;
    short* queryb = p;  p += LL * HH;    // 524288
    short* keyb   = p;  p += CC * HH;    // 262144
    short* Wqb    = p;  p += HH * HH;    // 262144
    short* Wkb    = p;  p += HH * HH;    // 262144
    short* relkb  = p;  p += 64 * HH;    // 32768 (51 rows valid, tail zeroed)
    short* qbuf   = p;  p += LL * HH;    // 524288
    short* kbuf   = p;  p += CC * HH;    // 262144
    float* Ssum   = (float*)p;           // 1024*8 f32
    float* Rbuf   = Ssum + LL * 8;       // 1024*64 f32 (R = q @ relk^T)

    k0_prep<<<512, 256, 0, stream>>>(query, key, Wq, Wk, relk,
                                     queryb, keyb, Wqb, Wkb, relkb, Rbuf);
    k1_proj<<<768, 64, 0, stream>>>(queryb, keyb, Wqb, Wkb, relkb, bq,
                                    qbuf, kbuf, Rbuf);
    k2_attn<<<512, 64, 0, stream>>>(qbuf, kbuf, rel, qlen, Rbuf, Ssum, out);
    k3_norm<<<512, 256, 0, stream>>>(Ssum, out);
}